// Round 1
// 437.747 us; speedup vs baseline: 1.0315x; 1.0315x over previous
//
#include <hip/hip_runtime.h>
#include <hip/hip_bf16.h>

typedef __attribute__((ext_vector_type(8))) short short8;
typedef __attribute__((ext_vector_type(16))) float f32x16;
typedef __attribute__((ext_vector_type(4))) float f32x4;

#define NN 8192      // nodes == classes
#define FIN 512
#define HD 64
#define LOG2E 1.44269504088896f

#if __has_builtin(__builtin_amdgcn_exp2f)
#define EXP2(x) __builtin_amdgcn_exp2f(x)
#else
#define EXP2(x) exp2f(x)
#endif

// ---------------- pack W2 -> 32x32x16 MFMA B-fragment order, + zero cnt ----------------
// B frag for (c32, kc): lane holds col = lane&31, k = kc*16 + (lane>>5)*8 + j
// w2p short index: ((c32*4 + kc)*64 + (k>>3 &1)*32 + col)*8 + (k&7)
__global__ void k_pack_zero(const float* __restrict__ W2, __hip_bfloat16* __restrict__ w2p,
                            int* __restrict__ cnt) {
    int i = blockIdx.x * blockDim.x + threadIdx.x;   // 0 .. 64*8192-1
    if (i < NN) cnt[i] = 0;
    int k  = i >> 13;            // 0..63
    int cc = i & 8191;
    int c32 = cc >> 5, cl = cc & 31;
    int kc = k >> 4, hh = (k >> 3) & 1, j = k & 7;
    int dsti = ((c32 * 4 + kc) * 64 + hh * 32 + cl) * 8 + j;
    w2p[dsti] = __float2bfloat16(W2[i]);
}

// ---------------- CSR build ----------------
__global__ void k_count(const int* __restrict__ dst, int E, int* __restrict__ cnt) {
    int e = blockIdx.x * blockDim.x + threadIdx.x;
    if (e < E) atomicAdd(&cnt[dst[e]], 1);
}

__global__ __launch_bounds__(1024) void k_scan(const int* __restrict__ cnt,
        int* __restrict__ offs, int* __restrict__ cursor, float* __restrict__ dinv) {
    __shared__ int wsh[16];
    int t = threadIdx.x;
    int lane = t & 63, wv = t >> 6;
    int v[8], loc[8];
    int s = 0;
#pragma unroll
    for (int j = 0; j < 8; ++j) { v[j] = cnt[t*8+j]; loc[j] = s; s += v[j]; }
    int inc = s;
#pragma unroll
    for (int d = 1; d < 64; d <<= 1) {
        int up = __shfl_up(inc, d, 64);
        if (lane >= d) inc += up;
    }
    if (lane == 63) wsh[wv] = inc;
    __syncthreads();
    if (t < 16) {
        int mv = wsh[t];
        int winc = mv;
#pragma unroll
        for (int d = 1; d < 16; d <<= 1) {
            int up = __shfl_up(winc, d, 16);
            if (t >= d) winc += up;
        }
        wsh[t] = winc - mv;   // exclusive wave base
    }
    __syncthreads();
    int base = wsh[wv] + (inc - s);
#pragma unroll
    for (int j = 0; j < 8; ++j) {
        int o = base + loc[j];
        offs[t*8+j]   = o;
        cursor[t*8+j] = o;
        dinv[t*8+j]   = rsqrtf((float)(v[j] + 1));  // +1 self loop
    }
    if (t == 1023) offs[NN] = base + s;
}

__global__ void k_scatter(const int* __restrict__ src, const int* __restrict__ dst, int E,
        int* __restrict__ cursor, int* __restrict__ ssrc) {
    int e = blockIdx.x * blockDim.x + threadIdx.x;
    if (e < E) {
        int pos = atomicAdd(&cursor[dst[e]], 1);
        ssrc[pos] = src[e];
    }
}

// ---------------- layer-1 GEMM: xws = (x @ W1) * dinv[row]  ----------------
// Inner loop: broadcast ds_read_b128 (1 per 4 kk per row) instead of 4x ds_read_b32,
// same accumulation order as v1 (bitwise identical result).
__global__ __launch_bounds__(256) void k_gemm1(const float* __restrict__ x,
        const float* __restrict__ W1, const float* __restrict__ dinv,
        float* __restrict__ xws) {
    __shared__ alignas(16) float Xs[16][132];
    int t = threadIdx.x;
    int c  = t & 63;
    int rg = t >> 6;
    int br = blockIdx.x * 16;
    float acc[4] = {0.f, 0.f, 0.f, 0.f};
    for (int k0 = 0; k0 < FIN; k0 += 128) {
        __syncthreads();
        int row_ld = t >> 4, kcol = (t & 15) * 8;
        const float* xp = x + (br + row_ld) * FIN + k0 + kcol;
        float4 v0 = *(const float4*)xp;
        float4 v1 = *(const float4*)(xp + 4);
        *(float4*)&Xs[row_ld][kcol]     = v0;
        *(float4*)&Xs[row_ld][kcol + 4] = v1;
        __syncthreads();
        int rg4 = rg * 4;
#pragma unroll 4
        for (int kk = 0; kk < 128; kk += 4) {
            f32x4 x0 = *(const f32x4*)&Xs[rg4 + 0][kk];
            f32x4 x1 = *(const f32x4*)&Xs[rg4 + 1][kk];
            f32x4 x2 = *(const f32x4*)&Xs[rg4 + 2][kk];
            f32x4 x3 = *(const f32x4*)&Xs[rg4 + 3][kk];
#pragma unroll
            for (int q = 0; q < 4; ++q) {
                float w = W1[(k0 + kk + q) * HD + c];
                acc[0] += x0[q] * w;
                acc[1] += x1[q] * w;
                acc[2] += x2[q] * w;
                acc[3] += x3[q] * w;
            }
        }
    }
#pragma unroll
    for (int r = 0; r < 4; ++r) {
        int row = br + rg*4 + r;
        xws[row * HD + c] = acc[r] * dinv[row];
    }
}

// ---------------- aggregation: one wave per node, lane = feature, 8-deep MLP ----------------
__global__ __launch_bounds__(256) void k_agg1(const float* __restrict__ xws,
        const int* __restrict__ offs, const int* __restrict__ ssrc,
        const float* __restrict__ dinv, const float* __restrict__ b1,
        float* __restrict__ hs) {
    int lane = threadIdx.x & 63;
    int node = (blockIdx.x << 2) + (threadIdx.x >> 6);
    const float* xp = xws + lane;
    float acc = xp[node * HD];
    int beg = offs[node], end = offs[node + 1];
    for (int base = beg; base < end; base += 64) {
        int rem = end - base;
        int n = rem < 64 ? rem : 64;
        int idx = (lane < n) ? ssrc[base + lane] : 0;
        int j = 0;
        for (; j + 8 <= n; j += 8) {
            int s0 = __shfl(idx, j+0, 64), s1 = __shfl(idx, j+1, 64);
            int s2 = __shfl(idx, j+2, 64), s3 = __shfl(idx, j+3, 64);
            int s4 = __shfl(idx, j+4, 64), s5 = __shfl(idx, j+5, 64);
            int s6 = __shfl(idx, j+6, 64), s7 = __shfl(idx, j+7, 64);
            float v0 = xp[s0*HD], v1 = xp[s1*HD], v2 = xp[s2*HD], v3 = xp[s3*HD];
            float v4 = xp[s4*HD], v5 = xp[s5*HD], v6 = xp[s6*HD], v7 = xp[s7*HD];
            acc += ((v0+v1)+(v2+v3)) + ((v4+v5)+(v6+v7));
        }
        for (; j < n; ++j) {
            int s = __shfl(idx, j, 64);
            acc += xp[s*HD];
        }
    }
    float dv = dinv[node];
    float h = fmaxf(acc * dv + b1[lane], 0.f);
    hs[node * HD + lane] = h * dv;                 // pre-scale for layer-2 messages
}

// Fallback-path agg2 (used only when ws is too small for the fused path)
__global__ __launch_bounds__(256) void k_agg2(const float* __restrict__ hs,
        const int* __restrict__ offs, const int* __restrict__ ssrc,
        const float* __restrict__ dinv, __hip_bfloat16* __restrict__ gbf) {
    int lane = threadIdx.x & 63;
    int node = (blockIdx.x << 2) + (threadIdx.x >> 6);
    const float* hp = hs + lane;
    float acc = hp[node * HD];
    int beg = offs[node], end = offs[node + 1];
    for (int base = beg; base < end; base += 64) {
        int rem = end - base;
        int n = rem < 64 ? rem : 64;
        int idx = (lane < n) ? ssrc[base + lane] : 0;
        int j = 0;
        for (; j + 8 <= n; j += 8) {
            int s0 = __shfl(idx, j+0, 64), s1 = __shfl(idx, j+1, 64);
            int s2 = __shfl(idx, j+2, 64), s3 = __shfl(idx, j+3, 64);
            int s4 = __shfl(idx, j+4, 64), s5 = __shfl(idx, j+5, 64);
            int s6 = __shfl(idx, j+6, 64), s7 = __shfl(idx, j+7, 64);
            float v0 = hp[s0*HD], v1 = hp[s1*HD], v2 = hp[s2*HD], v3 = hp[s3*HD];
            float v4 = hp[s4*HD], v5 = hp[s5*HD], v6 = hp[s6*HD], v7 = hp[s7*HD];
            acc += ((v0+v1)+(v2+v3)) + ((v4+v5)+(v6+v7));
        }
        for (; j < n; ++j) {
            int s = __shfl(idx, j, 64);
            acc += hp[s*HD];
        }
    }
    gbf[node * HD + lane] = __float2bfloat16(acc * dinv[node]);
}

// ---------------- v1 fused GEMM2 + log_softmax (fallback path, gbf input) ----------------
__global__ __launch_bounds__(512) void k_fused(
        const __hip_bfloat16* __restrict__ gbf,
        const __hip_bfloat16* __restrict__ w2p,
        const float* __restrict__ b2,
        float* __restrict__ out) {
    __shared__ float red[32][8];
    __shared__ float Lsh[32];
    const unsigned short* g  = (const unsigned short*)gbf;
    const unsigned short* wp = (const unsigned short*)w2p;
    int t = threadIdx.x;
    int lane = t & 63, wv = t >> 6;
    int cl = lane & 31, hh = lane >> 5;
    int row0 = blockIdx.x * 32;

    short8 a[4];
#pragma unroll
    for (int kc = 0; kc < 4; ++kc)
        a[kc] = *(const short8*)(g + (row0 + cl) * HD + kc*16 + hh*8);

    float sm[16];
#pragma unroll
    for (int r = 0; r < 16; ++r) sm[r] = 0.f;

    for (int it = 0; it < 32; ++it) {
        int c32 = wv * 32 + it;
        const unsigned short* bp = wp + c32 * 2048 + lane * 8;
        float bias = b2[c32 * 32 + cl];
        f32x16 d;
#pragma unroll
        for (int r = 0; r < 16; ++r) d[r] = 0.f;
#pragma unroll
        for (int kc = 0; kc < 4; ++kc) {
            short8 b = *(const short8*)(bp + kc * 512);
            d = __builtin_amdgcn_mfma_f32_32x32x16_bf16(a[kc], b, d, 0, 0, 0);
        }
#pragma unroll
        for (int r = 0; r < 16; ++r)
            sm[r] += EXP2((d[r] + bias) * LOG2E);
    }
#pragma unroll
    for (int r = 0; r < 16; ++r) {
#pragma unroll
        for (int msk = 1; msk < 32; msk <<= 1)
            sm[r] += __shfl_xor(sm[r], msk, 64);
    }
    if (cl == 0) {
#pragma unroll
        for (int r = 0; r < 16; ++r)
            red[(r & 3) + 8 * (r >> 2) + 4 * hh][wv] = sm[r];
    }
    __syncthreads();
    if (t < 32) {
        float s = 0.f;
#pragma unroll
        for (int j = 0; j < 8; ++j) s += red[t][j];
        Lsh[t] = logf(s);
    }
    __syncthreads();
    float L[16];
#pragma unroll
    for (int r = 0; r < 16; ++r)
        L[r] = Lsh[(r & 3) + 8 * (r >> 2) + 4 * hh];

    for (int it = 0; it < 32; ++it) {
        int c32 = wv * 32 + it;
        const unsigned short* bp = wp + c32 * 2048 + lane * 8;
        float bias = b2[c32 * 32 + cl];
        f32x16 d;
#pragma unroll
        for (int r = 0; r < 16; ++r) d[r] = 0.f;
#pragma unroll
        for (int kc = 0; kc < 4; ++kc) {
            short8 b = *(const short8*)(bp + kc * 512);
            d = __builtin_amdgcn_mfma_f32_32x32x16_bf16(a[kc], b, d, 0, 0, 0);
        }
        float* op = out + (size_t)row0 * NN + c32 * 32 + cl;
#pragma unroll
        for (int r = 0; r < 16; ++r) {
            int rp = (r & 3) + 8 * (r >> 2) + 4 * hh;
            __builtin_nontemporal_store(d[r] + bias - L[r], op + (size_t)rp * NN);
        }
    }
}

// ---------------- v2: agg2 fused into GEMM2 + log_softmax ----------------
// Block handles rows row0..row0+31. Head: 8 waves aggregate 4 nodes each (lane=feature)
// into LDS as bf16; A-frags built from LDS. hs must NOT alias out (lives in ws).
__global__ __launch_bounds__(512) void k_fused2(
        const float* __restrict__ hs,
        const int* __restrict__ offs, const int* __restrict__ ssrc,
        const float* __restrict__ dinv,
        const __hip_bfloat16* __restrict__ w2p,
        const float* __restrict__ b2,
        float* __restrict__ out) {
    __shared__ alignas(16) unsigned short gsh[32][72];   // stride 72 shorts = 144 B (16-B aligned rows)
    __shared__ float red[32][8];
    __shared__ float Lsh[32];
    const unsigned short* wp = (const unsigned short*)w2p;
    int t = threadIdx.x;
    int lane = t & 63, wv = t >> 6;
    int cl = lane & 31, hh = lane >> 5;
    int row0 = blockIdx.x * 32;

    // ---- fused aggregation head: wave wv aggregates rows wv*4 .. wv*4+3 ----
    const float* hp = hs + lane;
    for (int q = 0; q < 4; ++q) {
        int r = wv * 4 + q;
        int node = row0 + r;
        float acc = hp[node * HD];
        int beg = offs[node], end = offs[node + 1];
        for (int base = beg; base < end; base += 64) {
            int rem = end - base;
            int n = rem < 64 ? rem : 64;
            int idx = (lane < n) ? ssrc[base + lane] : 0;
            int j = 0;
            for (; j + 8 <= n; j += 8) {
                int s0 = __shfl(idx, j+0, 64), s1 = __shfl(idx, j+1, 64);
                int s2 = __shfl(idx, j+2, 64), s3 = __shfl(idx, j+3, 64);
                int s4 = __shfl(idx, j+4, 64), s5 = __shfl(idx, j+5, 64);
                int s6 = __shfl(idx, j+6, 64), s7 = __shfl(idx, j+7, 64);
                float v0 = hp[s0*HD], v1 = hp[s1*HD], v2 = hp[s2*HD], v3 = hp[s3*HD];
                float v4 = hp[s4*HD], v5 = hp[s5*HD], v6 = hp[s6*HD], v7 = hp[s7*HD];
                acc += ((v0+v1)+(v2+v3)) + ((v4+v5)+(v6+v7));
            }
            for (; j < n; ++j) {
                int s = __shfl(idx, j, 64);
                acc += hp[s*HD];
            }
        }
        __hip_bfloat16 hv = __float2bfloat16(acc * dinv[node]);
        gsh[r][lane] = *reinterpret_cast<unsigned short*>(&hv);
    }
    __syncthreads();

    // A fragments from LDS: A[row=cl][k = kc*16 + hh*8 + j]
    short8 a[4];
#pragma unroll
    for (int kc = 0; kc < 4; ++kc)
        a[kc] = *(const short8*)&gsh[cl][kc * 16 + hh * 8];

    const unsigned short* bpw = wp + (wv * 32) * 2048 + lane * 8;
    const float* bias_c = b2 + wv * 1024 + cl;

    float sm[16];
#pragma unroll
    for (int r = 0; r < 16; ++r) sm[r] = 0.f;

    // pass 1: sum of exp, with next-iter B-frag prefetch
    short8 bc[4];
#pragma unroll
    for (int kc = 0; kc < 4; ++kc) bc[kc] = *(const short8*)(bpw + kc * 512);
    for (int it = 0; it < 32; ++it) {
        int itn = (it + 1) & 31;
        const unsigned short* bq = bpw + itn * 2048;
        short8 bn[4];
#pragma unroll
        for (int kc = 0; kc < 4; ++kc) bn[kc] = *(const short8*)(bq + kc * 512);
        float bias = bias_c[it * 32];
        f32x16 d;
#pragma unroll
        for (int r = 0; r < 16; ++r) d[r] = 0.f;
#pragma unroll
        for (int kc = 0; kc < 4; ++kc)
            d = __builtin_amdgcn_mfma_f32_32x32x16_bf16(a[kc], bc[kc], d, 0, 0, 0);
#pragma unroll
        for (int r = 0; r < 16; ++r)
            sm[r] += EXP2((d[r] + bias) * LOG2E);
#pragma unroll
        for (int kc = 0; kc < 4; ++kc) bc[kc] = bn[kc];
    }
#pragma unroll
    for (int r = 0; r < 16; ++r) {
#pragma unroll
        for (int msk = 1; msk < 32; msk <<= 1)
            sm[r] += __shfl_xor(sm[r], msk, 64);
    }
    if (cl == 0) {
#pragma unroll
        for (int r = 0; r < 16; ++r)
            red[(r & 3) + 8 * (r >> 2) + 4 * hh][wv] = sm[r];
    }
    __syncthreads();
    if (t < 32) {
        float s = 0.f;
#pragma unroll
        for (int j = 0; j < 8; ++j) s += red[t][j];
        Lsh[t] = logf(s);
    }
    __syncthreads();
    float L[16];
#pragma unroll
    for (int r = 0; r < 16; ++r)
        L[r] = Lsh[(r & 3) + 8 * (r >> 2) + 4 * hh];

    // pass 2: recompute + coalesced nt stores, same prefetch pipeline
#pragma unroll
    for (int kc = 0; kc < 4; ++kc) bc[kc] = *(const short8*)(bpw + kc * 512);
    for (int it = 0; it < 32; ++it) {
        int itn = (it + 1) & 31;
        const unsigned short* bq = bpw + itn * 2048;
        short8 bn[4];
#pragma unroll
        for (int kc = 0; kc < 4; ++kc) bn[kc] = *(const short8*)(bq + kc * 512);
        int c32 = wv * 32 + it;
        float bias = bias_c[it * 32];
        f32x16 d;
#pragma unroll
        for (int r = 0; r < 16; ++r) d[r] = 0.f;
#pragma unroll
        for (int kc = 0; kc < 4; ++kc)
            d = __builtin_amdgcn_mfma_f32_32x32x16_bf16(a[kc], bc[kc], d, 0, 0, 0);
        float* op = out + (size_t)row0 * NN + c32 * 32 + cl;
#pragma unroll
        for (int r = 0; r < 16; ++r) {
            int rp = (r & 3) + 8 * (r >> 2) + 4 * hh;
            __builtin_nontemporal_store(d[r] + bias - L[r], op + (size_t)rp * NN);
        }
#pragma unroll
        for (int kc = 0; kc < 4; ++kc) bc[kc] = bn[kc];
    }
}

extern "C" void kernel_launch(void* const* d_in, const int* in_sizes, int n_in,
                              void* d_out, int out_size, void* d_ws, size_t ws_size,
                              hipStream_t stream) {
    const float* x  = (const float*)d_in[0];
    const int*   ei = (const int*)d_in[1];
    const float* W1 = (const float*)d_in[2];
    const float* b1 = (const float*)d_in[3];
    const float* W2 = (const float*)d_in[4];
    const float* b2 = (const float*)d_in[5];
    float* out = (float*)d_out;
    int E = in_sizes[1] / 2;
    const int* esrc = ei;
    const int* edst = ei + E;

    // ws layout: small tables @0..132K, w2p @192K (1 MB), [fused path] hs @192K+1M (2 MB)
    char* w = (char*)d_ws;
    int*   cnt    = (int*)(w);
    int*   offs   = (int*)(w + (32 << 10));
    int*   cursor = (int*)(w + (68 << 10));
    float* dinv   = (float*)(w + (100 << 10));
    __hip_bfloat16* w2p = (__hip_bfloat16*)(w + (192 << 10));

    size_t total = (size_t)NN * NN;
    size_t need_fused = (size_t)(192 << 10) + (1 << 20) + (size_t)NN * HD * sizeof(float);
    bool fused_path = ws_size >= need_fused;

    int eb = (E + 255) / 256;
    k_pack_zero<<<(HD * NN) / 256, 256, 0, stream>>>(W2, w2p, cnt);
    k_count  <<<eb, 256, 0, stream>>>(edst, E, cnt);
    k_scan   <<<1, 1024, 0, stream>>>(cnt, offs, cursor, dinv);

    if (fused_path) {
        // hs lives in ws (k_fused2 reads it while writing all of out);
        // xws/ssrc are dead before k_fused2 -> out tail is safe for them.
        float* hs   = (float*)(w + (192 << 10) + (1 << 20));
        float* xws  = out + total - (size_t)NN * HD;
        int*   ssrc = (int*)xws - E;
        k_scatter<<<eb, 256, 0, stream>>>(esrc, edst, E, cursor, ssrc);
        k_gemm1  <<<NN / 16, 256, 0, stream>>>(x, W1, dinv, xws);
        k_agg1   <<<NN / 4, 256, 0, stream>>>(xws, offs, ssrc, dinv, b1, hs);
        k_fused2 <<<NN / 32, 512, 0, stream>>>(hs, offs, ssrc, dinv, w2p, b2, out);
    } else {
        // v1 fallback: identical to the previous verified version.
        __hip_bfloat16* gbf = (__hip_bfloat16*)(w + (192 << 10) + (1 << 20));
        float* hs   = out + total - (size_t)NN * HD;
        float* xws  = hs  - (size_t)NN * HD;
        int*   ssrc = (int*)xws - E;
        k_scatter<<<eb, 256, 0, stream>>>(esrc, edst, E, cursor, ssrc);
        k_gemm1  <<<NN / 16, 256, 0, stream>>>(x, W1, dinv, xws);
        k_agg1   <<<NN / 4, 256, 0, stream>>>(xws, offs, ssrc, dinv, b1, hs);
        k_agg2   <<<NN / 4, 256, 0, stream>>>(hs, offs, ssrc, dinv, gbf);
        k_fused  <<<NN / 32, 512, 0, stream>>>(gbf, w2p, b2, out);
    }
}

// Round 2
// 428.922 us; speedup vs baseline: 1.0527x; 1.0206x over previous
//
#include <hip/hip_runtime.h>
#include <hip/hip_bf16.h>

typedef __attribute__((ext_vector_type(8))) short short8;
typedef __attribute__((ext_vector_type(16))) float f32x16;
typedef __attribute__((ext_vector_type(4))) float f32x4;

#define NN 8192      // nodes == classes
#define FIN 512
#define HD 64
#define LOG2E 1.44269504088896f

#if __has_builtin(__builtin_amdgcn_exp2f)
#define EXP2(x) __builtin_amdgcn_exp2f(x)
#else
#define EXP2(x) exp2f(x)
#endif

// ---------------- pack W2 -> 32x32x16 MFMA B-fragment order, + zero cnt ----------------
// Consumer (k_fused*): B frag for (c32, kc): lane holds col = lane&31, k = kc*16 + (lane>>5)*8 + j
// short index = c32*2048 + kc*512 + (hh*32+cl)*8 + j.
// One thread per short8 group i = c32*256 + kc*64 + hh*32 + cl -> one contiguous 16-B store.
__global__ void k_pack_zero(const float* __restrict__ W2, __hip_bfloat16* __restrict__ w2p,
                            int* __restrict__ cnt) {
    int i = blockIdx.x * blockDim.x + threadIdx.x;   // 0 .. 65535
    if (i < NN) cnt[i] = 0;
    int cl  = i & 31;
    int hh  = (i >> 5) & 1;
    int kc  = (i >> 6) & 3;
    int c32 = i >> 8;
    const float* wsrc = W2 + (size_t)(kc * 16 + hh * 8) * NN + c32 * 32 + cl;
    union { short8 v; unsigned short u[8]; } ov;
#pragma unroll
    for (int j = 0; j < 8; ++j) {
        __hip_bfloat16 hv = __float2bfloat16(wsrc[(size_t)j * NN]);
        ov.u[j] = *reinterpret_cast<unsigned short*>(&hv);
    }
    ((short8*)w2p)[i] = ov.v;
}

// ---------------- CSR build ----------------
__global__ void k_count(const int* __restrict__ dst, int E, int* __restrict__ cnt) {
    int e4 = blockIdx.x * blockDim.x + threadIdx.x;
    int e = e4 * 4;
    if (e + 3 < E) {
        int4 d = ((const int4*)dst)[e4];
        atomicAdd(&cnt[d.x], 1);
        atomicAdd(&cnt[d.y], 1);
        atomicAdd(&cnt[d.z], 1);
        atomicAdd(&cnt[d.w], 1);
    } else {
        for (int q = e; q < E; ++q) atomicAdd(&cnt[dst[q]], 1);
    }
}

__global__ __launch_bounds__(1024) void k_scan(const int* __restrict__ cnt,
        int* __restrict__ offs, int* __restrict__ cursor, float* __restrict__ dinv) {
    __shared__ int wsh[16];
    int t = threadIdx.x;
    int lane = t & 63, wv = t >> 6;
    int4 va = ((const int4*)cnt)[t * 2];
    int4 vb = ((const int4*)cnt)[t * 2 + 1];
    int v[8] = {va.x, va.y, va.z, va.w, vb.x, vb.y, vb.z, vb.w};
    int loc[8];
    int s = 0;
#pragma unroll
    for (int j = 0; j < 8; ++j) { loc[j] = s; s += v[j]; }
    int inc = s;
#pragma unroll
    for (int d = 1; d < 64; d <<= 1) {
        int up = __shfl_up(inc, d, 64);
        if (lane >= d) inc += up;
    }
    if (lane == 63) wsh[wv] = inc;
    __syncthreads();
    if (t < 16) {
        int mv = wsh[t];
        int winc = mv;
#pragma unroll
        for (int d = 1; d < 16; d <<= 1) {
            int up = __shfl_up(winc, d, 16);
            if (t >= d) winc += up;
        }
        wsh[t] = winc - mv;   // exclusive wave base
    }
    __syncthreads();
    int base = wsh[wv] + (inc - s);
    int4 oa = {base + loc[0], base + loc[1], base + loc[2], base + loc[3]};
    int4 ob = {base + loc[4], base + loc[5], base + loc[6], base + loc[7]};
    ((int4*)offs)[t * 2]     = oa;
    ((int4*)offs)[t * 2 + 1] = ob;
    ((int4*)cursor)[t * 2]     = oa;
    ((int4*)cursor)[t * 2 + 1] = ob;
    float4 da = {rsqrtf((float)(v[0] + 1)), rsqrtf((float)(v[1] + 1)),
                 rsqrtf((float)(v[2] + 1)), rsqrtf((float)(v[3] + 1))};
    float4 db = {rsqrtf((float)(v[4] + 1)), rsqrtf((float)(v[5] + 1)),
                 rsqrtf((float)(v[6] + 1)), rsqrtf((float)(v[7] + 1))};
    ((float4*)dinv)[t * 2]     = da;
    ((float4*)dinv)[t * 2 + 1] = db;
    if (t == 1023) offs[NN] = base + s;
}

// ---------------- merged: layer-1 GEMM (blocks 0..NN/16-1)  ||  CSR scatter ----------------
// gemm1: xws = (x @ W1) * dinv[row]; scatter: ssrc[cursor[dst]++] = src.
// Independent ops overlapped in one dispatch (single stream would serialize them).
__global__ __launch_bounds__(256) void k_mid(const float* __restrict__ x,
        const float* __restrict__ W1, const float* __restrict__ dinv,
        float* __restrict__ xws,
        const int* __restrict__ src, const int* __restrict__ dst, int E,
        int* __restrict__ cursor, int* __restrict__ ssrc) {
    __shared__ alignas(16) float Xs[16][132];
    int t = threadIdx.x;
    if (blockIdx.x >= NN / 16) {
        // ---- scatter branch ----
        int e4 = (blockIdx.x - NN / 16) * 256 + t;
        int e = e4 * 4;
        if (e + 3 < E) {
            int4 d = ((const int4*)dst)[e4];
            int4 sv = ((const int4*)src)[e4];
            int p0 = atomicAdd(&cursor[d.x], 1); ssrc[p0] = sv.x;
            int p1 = atomicAdd(&cursor[d.y], 1); ssrc[p1] = sv.y;
            int p2 = atomicAdd(&cursor[d.z], 1); ssrc[p2] = sv.z;
            int p3 = atomicAdd(&cursor[d.w], 1); ssrc[p3] = sv.w;
        } else {
            for (int q = e; q < E; ++q) {
                int pos = atomicAdd(&cursor[dst[q]], 1);
                ssrc[pos] = src[q];
            }
        }
        return;
    }
    // ---- gemm1 branch ----
    int c  = t & 63;
    int rg = t >> 6;
    int br = blockIdx.x * 16;
    float acc[4] = {0.f, 0.f, 0.f, 0.f};
    for (int k0 = 0; k0 < FIN; k0 += 128) {
        __syncthreads();
        int row_ld = t >> 4, kcol = (t & 15) * 8;
        const float* xp = x + (br + row_ld) * FIN + k0 + kcol;
        float4 v0 = *(const float4*)xp;
        float4 v1 = *(const float4*)(xp + 4);
        *(float4*)&Xs[row_ld][kcol]     = v0;
        *(float4*)&Xs[row_ld][kcol + 4] = v1;
        __syncthreads();
        int rg4 = rg * 4;
#pragma unroll 4
        for (int kk = 0; kk < 128; kk += 4) {
            f32x4 x0 = *(const f32x4*)&Xs[rg4 + 0][kk];
            f32x4 x1 = *(const f32x4*)&Xs[rg4 + 1][kk];
            f32x4 x2 = *(const f32x4*)&Xs[rg4 + 2][kk];
            f32x4 x3 = *(const f32x4*)&Xs[rg4 + 3][kk];
#pragma unroll
            for (int q = 0; q < 4; ++q) {
                float w = W1[(k0 + kk + q) * HD + c];
                acc[0] += x0[q] * w;
                acc[1] += x1[q] * w;
                acc[2] += x2[q] * w;
                acc[3] += x3[q] * w;
            }
        }
    }
#pragma unroll
    for (int r = 0; r < 4; ++r) {
        int row = br + rg*4 + r;
        xws[row * HD + c] = acc[r] * dinv[row];
    }
}

// ---------------- aggregation: one wave per node, lane = feature, 8-deep MLP ----------------
__global__ __launch_bounds__(256) void k_agg1(const float* __restrict__ xws,
        const int* __restrict__ offs, const int* __restrict__ ssrc,
        const float* __restrict__ dinv, const float* __restrict__ b1,
        float* __restrict__ hs) {
    int lane = threadIdx.x & 63;
    int node = (blockIdx.x << 2) + (threadIdx.x >> 6);
    const float* xp = xws + lane;
    float acc = xp[node * HD];
    int beg = offs[node], end = offs[node + 1];
    for (int base = beg; base < end; base += 64) {
        int rem = end - base;
        int n = rem < 64 ? rem : 64;
        int idx = (lane < n) ? ssrc[base + lane] : 0;
        int j = 0;
        for (; j + 8 <= n; j += 8) {
            int s0 = __shfl(idx, j+0, 64), s1 = __shfl(idx, j+1, 64);
            int s2 = __shfl(idx, j+2, 64), s3 = __shfl(idx, j+3, 64);
            int s4 = __shfl(idx, j+4, 64), s5 = __shfl(idx, j+5, 64);
            int s6 = __shfl(idx, j+6, 64), s7 = __shfl(idx, j+7, 64);
            float v0 = xp[s0*HD], v1 = xp[s1*HD], v2 = xp[s2*HD], v3 = xp[s3*HD];
            float v4 = xp[s4*HD], v5 = xp[s5*HD], v6 = xp[s6*HD], v7 = xp[s7*HD];
            acc += ((v0+v1)+(v2+v3)) + ((v4+v5)+(v6+v7));
        }
        for (; j < n; ++j) {
            int s = __shfl(idx, j, 64);
            acc += xp[s*HD];
        }
    }
    float dv = dinv[node];
    float h = fmaxf(acc * dv + b1[lane], 0.f);
    hs[node * HD + lane] = h * dv;                 // pre-scale for layer-2 messages
}

// Fallback-path agg2 (used only when ws is too small for the fused path)
__global__ __launch_bounds__(256) void k_agg2(const float* __restrict__ hs,
        const int* __restrict__ offs, const int* __restrict__ ssrc,
        const float* __restrict__ dinv, __hip_bfloat16* __restrict__ gbf) {
    int lane = threadIdx.x & 63;
    int node = (blockIdx.x << 2) + (threadIdx.x >> 6);
    const float* hp = hs + lane;
    float acc = hp[node * HD];
    int beg = offs[node], end = offs[node + 1];
    for (int base = beg; base < end; base += 64) {
        int rem = end - base;
        int n = rem < 64 ? rem : 64;
        int idx = (lane < n) ? ssrc[base + lane] : 0;
        int j = 0;
        for (; j + 8 <= n; j += 8) {
            int s0 = __shfl(idx, j+0, 64), s1 = __shfl(idx, j+1, 64);
            int s2 = __shfl(idx, j+2, 64), s3 = __shfl(idx, j+3, 64);
            int s4 = __shfl(idx, j+4, 64), s5 = __shfl(idx, j+5, 64);
            int s6 = __shfl(idx, j+6, 64), s7 = __shfl(idx, j+7, 64);
            float v0 = hp[s0*HD], v1 = hp[s1*HD], v2 = hp[s2*HD], v3 = hp[s3*HD];
            float v4 = hp[s4*HD], v5 = hp[s5*HD], v6 = hp[s6*HD], v7 = hp[s7*HD];
            acc += ((v0+v1)+(v2+v3)) + ((v4+v5)+(v6+v7));
        }
        for (; j < n; ++j) {
            int s = __shfl(idx, j, 64);
            acc += hp[s*HD];
        }
    }
    gbf[node * HD + lane] = __float2bfloat16(acc * dinv[node]);
}

// ---------------- v1 fused GEMM2 + log_softmax (fallback path, gbf input) ----------------
__global__ __launch_bounds__(512) void k_fused(
        const __hip_bfloat16* __restrict__ gbf,
        const __hip_bfloat16* __restrict__ w2p,
        const float* __restrict__ b2,
        float* __restrict__ out) {
    __shared__ float red[32][8];
    __shared__ float Lsh[32];
    const unsigned short* g  = (const unsigned short*)gbf;
    const unsigned short* wp = (const unsigned short*)w2p;
    int t = threadIdx.x;
    int lane = t & 63, wv = t >> 6;
    int cl = lane & 31, hh = lane >> 5;
    int row0 = blockIdx.x * 32;

    short8 a[4];
#pragma unroll
    for (int kc = 0; kc < 4; ++kc)
        a[kc] = *(const short8*)(g + (row0 + cl) * HD + kc*16 + hh*8);

    float sm[16];
#pragma unroll
    for (int r = 0; r < 16; ++r) sm[r] = 0.f;

    for (int it = 0; it < 32; ++it) {
        int c32 = wv * 32 + it;
        const unsigned short* bp = wp + c32 * 2048 + lane * 8;
        float bias = b2[c32 * 32 + cl];
        f32x16 d;
#pragma unroll
        for (int r = 0; r < 16; ++r) d[r] = 0.f;
#pragma unroll
        for (int kc = 0; kc < 4; ++kc) {
            short8 b = *(const short8*)(bp + kc * 512);
            d = __builtin_amdgcn_mfma_f32_32x32x16_bf16(a[kc], b, d, 0, 0, 0);
        }
#pragma unroll
        for (int r = 0; r < 16; ++r)
            sm[r] += EXP2((d[r] + bias) * LOG2E);
    }
#pragma unroll
    for (int r = 0; r < 16; ++r) {
#pragma unroll
        for (int msk = 1; msk < 32; msk <<= 1)
            sm[r] += __shfl_xor(sm[r], msk, 64);
    }
    if (cl == 0) {
#pragma unroll
        for (int r = 0; r < 16; ++r)
            red[(r & 3) + 8 * (r >> 2) + 4 * hh][wv] = sm[r];
    }
    __syncthreads();
    if (t < 32) {
        float s = 0.f;
#pragma unroll
        for (int j = 0; j < 8; ++j) s += red[t][j];
        Lsh[t] = logf(s);
    }
    __syncthreads();
    float L[16];
#pragma unroll
    for (int r = 0; r < 16; ++r)
        L[r] = Lsh[(r & 3) + 8 * (r >> 2) + 4 * hh];

    for (int it = 0; it < 32; ++it) {
        int c32 = wv * 32 + it;
        const unsigned short* bp = wp + c32 * 2048 + lane * 8;
        float bias = b2[c32 * 32 + cl];
        f32x16 d;
#pragma unroll
        for (int r = 0; r < 16; ++r) d[r] = 0.f;
#pragma unroll
        for (int kc = 0; kc < 4; ++kc) {
            short8 b = *(const short8*)(bp + kc * 512);
            d = __builtin_amdgcn_mfma_f32_32x32x16_bf16(a[kc], b, d, 0, 0, 0);
        }
        float* op = out + (size_t)row0 * NN + c32 * 32 + cl;
#pragma unroll
        for (int r = 0; r < 16; ++r) {
            int rp = (r & 3) + 8 * (r >> 2) + 4 * hh;
            __builtin_nontemporal_store(d[r] + bias - L[r], op + (size_t)rp * NN);
        }
    }
}

// ---------------- v2: agg2 fused into GEMM2 + log_softmax ----------------
__global__ __launch_bounds__(512) void k_fused2(
        const float* __restrict__ hs,
        const int* __restrict__ offs, const int* __restrict__ ssrc,
        const float* __restrict__ dinv,
        const __hip_bfloat16* __restrict__ w2p,
        const float* __restrict__ b2,
        float* __restrict__ out) {
    __shared__ alignas(16) unsigned short gsh[32][72];
    __shared__ float red[32][8];
    __shared__ float Lsh[32];
    const unsigned short* wp = (const unsigned short*)w2p;
    int t = threadIdx.x;
    int lane = t & 63, wv = t >> 6;
    int cl = lane & 31, hh = lane >> 5;
    int row0 = blockIdx.x * 32;

    // ---- fused aggregation head: wave wv aggregates rows wv*4 .. wv*4+3 ----
    const float* hp = hs + lane;
    for (int q = 0; q < 4; ++q) {
        int r = wv * 4 + q;
        int node = row0 + r;
        float acc = hp[node * HD];
        int beg = offs[node], end = offs[node + 1];
        for (int base = beg; base < end; base += 64) {
            int rem = end - base;
            int n = rem < 64 ? rem : 64;
            int idx = (lane < n) ? ssrc[base + lane] : 0;
            int j = 0;
            for (; j + 8 <= n; j += 8) {
                int s0 = __shfl(idx, j+0, 64), s1 = __shfl(idx, j+1, 64);
                int s2 = __shfl(idx, j+2, 64), s3 = __shfl(idx, j+3, 64);
                int s4 = __shfl(idx, j+4, 64), s5 = __shfl(idx, j+5, 64);
                int s6 = __shfl(idx, j+6, 64), s7 = __shfl(idx, j+7, 64);
                float v0 = hp[s0*HD], v1 = hp[s1*HD], v2 = hp[s2*HD], v3 = hp[s3*HD];
                float v4 = hp[s4*HD], v5 = hp[s5*HD], v6 = hp[s6*HD], v7 = hp[s7*HD];
                acc += ((v0+v1)+(v2+v3)) + ((v4+v5)+(v6+v7));
            }
            for (; j < n; ++j) {
                int s = __shfl(idx, j, 64);
                acc += hp[s*HD];
            }
        }
        __hip_bfloat16 hv = __float2bfloat16(acc * dinv[node]);
        gsh[r][lane] = *reinterpret_cast<unsigned short*>(&hv);
    }
    __syncthreads();

    short8 a[4];
#pragma unroll
    for (int kc = 0; kc < 4; ++kc)
        a[kc] = *(const short8*)&gsh[cl][kc * 16 + hh * 8];

    const unsigned short* bpw = wp + (wv * 32) * 2048 + lane * 8;
    const float* bias_c = b2 + wv * 1024 + cl;

    float sm[16];
#pragma unroll
    for (int r = 0; r < 16; ++r) sm[r] = 0.f;

    short8 bc[4];
#pragma unroll
    for (int kc = 0; kc < 4; ++kc) bc[kc] = *(const short8*)(bpw + kc * 512);
    for (int it = 0; it < 32; ++it) {
        int itn = (it + 1) & 31;
        const unsigned short* bq = bpw + itn * 2048;
        short8 bn[4];
#pragma unroll
        for (int kc = 0; kc < 4; ++kc) bn[kc] = *(const short8*)(bq + kc * 512);
        float bias = bias_c[it * 32];
        f32x16 d;
#pragma unroll
        for (int r = 0; r < 16; ++r) d[r] = 0.f;
#pragma unroll
        for (int kc = 0; kc < 4; ++kc)
            d = __builtin_amdgcn_mfma_f32_32x32x16_bf16(a[kc], bc[kc], d, 0, 0, 0);
#pragma unroll
        for (int r = 0; r < 16; ++r)
            sm[r] += EXP2((d[r] + bias) * LOG2E);
#pragma unroll
        for (int kc = 0; kc < 4; ++kc) bc[kc] = bn[kc];
    }
#pragma unroll
    for (int r = 0; r < 16; ++r) {
#pragma unroll
        for (int msk = 1; msk < 32; msk <<= 1)
            sm[r] += __shfl_xor(sm[r], msk, 64);
    }
    if (cl == 0) {
#pragma unroll
        for (int r = 0; r < 16; ++r)
            red[(r & 3) + 8 * (r >> 2) + 4 * hh][wv] = sm[r];
    }
    __syncthreads();
    if (t < 32) {
        float s = 0.f;
#pragma unroll
        for (int j = 0; j < 8; ++j) s += red[t][j];
        Lsh[t] = logf(s);
    }
    __syncthreads();
    float L[16];
#pragma unroll
    for (int r = 0; r < 16; ++r)
        L[r] = Lsh[(r & 3) + 8 * (r >> 2) + 4 * hh];

#pragma unroll
    for (int kc = 0; kc < 4; ++kc) bc[kc] = *(const short8*)(bpw + kc * 512);
    for (int it = 0; it < 32; ++it) {
        int itn = (it + 1) & 31;
        const unsigned short* bq = bpw + itn * 2048;
        short8 bn[4];
#pragma unroll
        for (int kc = 0; kc < 4; ++kc) bn[kc] = *(const short8*)(bq + kc * 512);
        int c32 = wv * 32 + it;
        float bias = bias_c[it * 32];
        f32x16 d;
#pragma unroll
        for (int r = 0; r < 16; ++r) d[r] = 0.f;
#pragma unroll
        for (int kc = 0; kc < 4; ++kc)
            d = __builtin_amdgcn_mfma_f32_32x32x16_bf16(a[kc], bc[kc], d, 0, 0, 0);
        float* op = out + (size_t)row0 * NN + c32 * 32 + cl;
#pragma unroll
        for (int r = 0; r < 16; ++r) {
            int rp = (r & 3) + 8 * (r >> 2) + 4 * hh;
            __builtin_nontemporal_store(d[r] + bias - L[r], op + (size_t)rp * NN);
        }
#pragma unroll
        for (int kc = 0; kc < 4; ++kc) bc[kc] = bn[kc];
    }
}

extern "C" void kernel_launch(void* const* d_in, const int* in_sizes, int n_in,
                              void* d_out, int out_size, void* d_ws, size_t ws_size,
                              hipStream_t stream) {
    const float* x  = (const float*)d_in[0];
    const int*   ei = (const int*)d_in[1];
    const float* W1 = (const float*)d_in[2];
    const float* b1 = (const float*)d_in[3];
    const float* W2 = (const float*)d_in[4];
    const float* b2 = (const float*)d_in[5];
    float* out = (float*)d_out;
    int E = in_sizes[1] / 2;
    const int* esrc = ei;
    const int* edst = ei + E;

    char* w = (char*)d_ws;
    int*   cnt    = (int*)(w);
    int*   offs   = (int*)(w + (32 << 10));
    int*   cursor = (int*)(w + (68 << 10));
    float* dinv   = (float*)(w + (100 << 10));
    __hip_bfloat16* w2p = (__hip_bfloat16*)(w + (192 << 10));

    size_t total = (size_t)NN * NN;
    size_t need_fused = (size_t)(192 << 10) + (1 << 20) + (size_t)NN * HD * sizeof(float);
    bool fused_path = ws_size >= need_fused;

    int cb = ((E + 3) / 4 + 255) / 256;          // count/scatter blocks (int4 edges)
    int gb = NN / 16;                            // gemm1 blocks

    k_pack_zero<<<(HD * NN / 8) / 256, 256, 0, stream>>>(W2, w2p, cnt);
    k_count  <<<cb, 256, 0, stream>>>(edst, E, cnt);
    k_scan   <<<1, 1024, 0, stream>>>(cnt, offs, cursor, dinv);

    if (fused_path) {
        // hs lives in ws (k_fused2 reads it while writing all of out);
        // xws/ssrc are dead before k_fused2 -> out tail is safe for them.
        float* hs   = (float*)(w + (192 << 10) + (1 << 20));
        float* xws  = out + total - (size_t)NN * HD;
        int*   ssrc = (int*)xws - E;
        k_mid    <<<gb + cb, 256, 0, stream>>>(x, W1, dinv, xws, esrc, edst, E, cursor, ssrc);
        k_agg1   <<<NN / 4, 256, 0, stream>>>(xws, offs, ssrc, dinv, b1, hs);
        k_fused2 <<<NN / 32, 512, 0, stream>>>(hs, offs, ssrc, dinv, w2p, b2, out);
    } else {
        // v1-style fallback (agg2 + k_fused), intermediates in out tail.
        __hip_bfloat16* gbf = (__hip_bfloat16*)(w + (192 << 10) + (1 << 20));
        float* hs   = out + total - (size_t)NN * HD;
        float* xws  = hs  - (size_t)NN * HD;
        int*   ssrc = (int*)xws - E;
        k_mid    <<<gb + cb, 256, 0, stream>>>(x, W1, dinv, xws, esrc, edst, E, cursor, ssrc);
        k_agg1   <<<NN / 4, 256, 0, stream>>>(xws, offs, ssrc, dinv, b1, hs);
        k_agg2   <<<NN / 4, 256, 0, stream>>>(hs, offs, ssrc, dinv, gbf);
        k_fused  <<<NN / 32, 512, 0, stream>>>(gbf, w2p, b2, out);
    }
}

// Round 5
// 426.745 us; speedup vs baseline: 1.0581x; 1.0051x over previous
//
#include <hip/hip_runtime.h>
#include <hip/hip_bf16.h>

typedef __attribute__((ext_vector_type(8))) short short8;
typedef __attribute__((ext_vector_type(16))) float f32x16;
typedef __attribute__((ext_vector_type(4))) float f32x4;

#define NN 8192      // nodes == classes
#define FIN 512
#define HD 64
#define LOG2E 1.44269504088896f

#if __has_builtin(__builtin_amdgcn_exp2f)
#define EXP2(x) __builtin_amdgcn_exp2f(x)
#else
#define EXP2(x) exp2f(x)
#endif

// ---------------- zero cnt (graph-capture-safe, stream-ordered) ----------------
__global__ __launch_bounds__(1024) void k_zero(int* __restrict__ cnt) {
    int t = threadIdx.x;                          // 1024 threads, 8 ints each
    int4 z = {0, 0, 0, 0};
    ((int4*)cnt)[t * 2]     = z;
    ((int4*)cnt)[t * 2 + 1] = z;
}

// ---------------- merged front: W2 pack (blocks 0..pb-1)  ||  degree count ----------------
// Requires cnt pre-zeroed (k_zero runs before this dispatch).
// pack: w2p short index = c32*2048 + kc*512 + (hh*32+cl)*8 + j; one thread per short8 group
//       i = c32*256 + kc*64 + hh*32 + cl -> one contiguous 16-B store.
__global__ void k_front(const float* __restrict__ W2, __hip_bfloat16* __restrict__ w2p,
                        const int* __restrict__ dst, int E, int* __restrict__ cnt,
                        int packBlocks) {
    int t = threadIdx.x;
    if ((int)blockIdx.x < packBlocks) {
        int i = blockIdx.x * 256 + t;              // 0 .. 65535
        int cl  = i & 31;
        int hh  = (i >> 5) & 1;
        int kc  = (i >> 6) & 3;
        int c32 = i >> 8;
        const float* wsrc = W2 + (size_t)(kc * 16 + hh * 8) * NN + c32 * 32 + cl;
        union { short8 v; unsigned short u[8]; } ov;
#pragma unroll
        for (int j = 0; j < 8; ++j) {
            __hip_bfloat16 hv = __float2bfloat16(wsrc[(size_t)j * NN]);
            ov.u[j] = *reinterpret_cast<unsigned short*>(&hv);
        }
        ((short8*)w2p)[i] = ov.v;
        return;
    }
    // ---- count branch: 4 edges / thread ----
    int e4 = (blockIdx.x - packBlocks) * 256 + t;
    int e = e4 * 4;
    if (e + 3 < E) {
        int4 d = ((const int4*)dst)[e4];
        atomicAdd(&cnt[d.x], 1);
        atomicAdd(&cnt[d.y], 1);
        atomicAdd(&cnt[d.z], 1);
        atomicAdd(&cnt[d.w], 1);
    } else {
        for (int q = e; q < E; ++q) atomicAdd(&cnt[dst[q]], 1);
    }
}

__global__ __launch_bounds__(1024) void k_scan(const int* __restrict__ cnt,
        int* __restrict__ offs, int* __restrict__ cursor, float* __restrict__ dinv) {
    __shared__ int wsh[16];
    int t = threadIdx.x;
    int lane = t & 63, wv = t >> 6;
    int4 va = ((const int4*)cnt)[t * 2];
    int4 vb = ((const int4*)cnt)[t * 2 + 1];
    int v[8] = {va.x, va.y, va.z, va.w, vb.x, vb.y, vb.z, vb.w};
    int loc[8];
    int s = 0;
#pragma unroll
    for (int j = 0; j < 8; ++j) { loc[j] = s; s += v[j]; }
    int inc = s;
#pragma unroll
    for (int d = 1; d < 64; d <<= 1) {
        int up = __shfl_up(inc, d, 64);
        if (lane >= d) inc += up;
    }
    if (lane == 63) wsh[wv] = inc;
    __syncthreads();
    if (t < 16) {
        int mv = wsh[t];
        int winc = mv;
#pragma unroll
        for (int d = 1; d < 16; d <<= 1) {
            int up = __shfl_up(winc, d, 16);
            if (t >= d) winc += up;
        }
        wsh[t] = winc - mv;   // exclusive wave base
    }
    __syncthreads();
    int base = wsh[wv] + (inc - s);
    int4 oa = {base + loc[0], base + loc[1], base + loc[2], base + loc[3]};
    int4 ob = {base + loc[4], base + loc[5], base + loc[6], base + loc[7]};
    ((int4*)offs)[t * 2]     = oa;
    ((int4*)offs)[t * 2 + 1] = ob;
    ((int4*)cursor)[t * 2]     = oa;
    ((int4*)cursor)[t * 2 + 1] = ob;
    float4 da = {rsqrtf((float)(v[0] + 1)), rsqrtf((float)(v[1] + 1)),
                 rsqrtf((float)(v[2] + 1)), rsqrtf((float)(v[3] + 1))};
    float4 db = {rsqrtf((float)(v[4] + 1)), rsqrtf((float)(v[5] + 1)),
                 rsqrtf((float)(v[6] + 1)), rsqrtf((float)(v[7] + 1))};
    ((float4*)dinv)[t * 2]     = da;
    ((float4*)dinv)[t * 2 + 1] = db;
    if (t == 1023) offs[NN] = base + s;
}

// ---------------- merged: layer-1 GEMM (blocks 0..NN/16-1)  ||  CSR scatter ----------------
__global__ __launch_bounds__(256) void k_mid(const float* __restrict__ x,
        const float* __restrict__ W1, const float* __restrict__ dinv,
        float* __restrict__ xws,
        const int* __restrict__ src, const int* __restrict__ dst, int E,
        int* __restrict__ cursor, int* __restrict__ ssrc) {
    __shared__ alignas(16) float Xs[16][132];
    int t = threadIdx.x;
    if (blockIdx.x >= NN / 16) {
        // ---- scatter branch ----
        int e4 = (blockIdx.x - NN / 16) * 256 + t;
        int e = e4 * 4;
        if (e + 3 < E) {
            int4 d = ((const int4*)dst)[e4];
            int4 sv = ((const int4*)src)[e4];
            int p0 = atomicAdd(&cursor[d.x], 1); ssrc[p0] = sv.x;
            int p1 = atomicAdd(&cursor[d.y], 1); ssrc[p1] = sv.y;
            int p2 = atomicAdd(&cursor[d.z], 1); ssrc[p2] = sv.z;
            int p3 = atomicAdd(&cursor[d.w], 1); ssrc[p3] = sv.w;
        } else {
            for (int q = e; q < E; ++q) {
                int pos = atomicAdd(&cursor[dst[q]], 1);
                ssrc[pos] = src[q];
            }
        }
        return;
    }
    // ---- gemm1 branch ----
    int c  = t & 63;
    int rg = t >> 6;
    int br = blockIdx.x * 16;
    float acc[4] = {0.f, 0.f, 0.f, 0.f};
    for (int k0 = 0; k0 < FIN; k0 += 128) {
        __syncthreads();
        int row_ld = t >> 4, kcol = (t & 15) * 8;
        const float* xp = x + (br + row_ld) * FIN + k0 + kcol;
        f32x4 v0 = __builtin_nontemporal_load((const f32x4*)xp);
        f32x4 v1 = __builtin_nontemporal_load((const f32x4*)(xp + 4));
        *(f32x4*)&Xs[row_ld][kcol]     = v0;
        *(f32x4*)&Xs[row_ld][kcol + 4] = v1;
        __syncthreads();
        int rg4 = rg * 4;
#pragma unroll 4
        for (int kk = 0; kk < 128; kk += 4) {
            f32x4 x0 = *(const f32x4*)&Xs[rg4 + 0][kk];
            f32x4 x1 = *(const f32x4*)&Xs[rg4 + 1][kk];
            f32x4 x2 = *(const f32x4*)&Xs[rg4 + 2][kk];
            f32x4 x3 = *(const f32x4*)&Xs[rg4 + 3][kk];
#pragma unroll
            for (int q = 0; q < 4; ++q) {
                float w = W1[(k0 + kk + q) * HD + c];
                acc[0] += x0[q] * w;
                acc[1] += x1[q] * w;
                acc[2] += x2[q] * w;
                acc[3] += x3[q] * w;
            }
        }
    }
#pragma unroll
    for (int r = 0; r < 4; ++r) {
        int row = br + rg*4 + r;
        xws[row * HD + c] = acc[r] * dinv[row];
    }
}

// ---------------- aggregation: one wave per node, lane = feature, 8-deep MLP ----------------
__global__ __launch_bounds__(256) void k_agg1(const float* __restrict__ xws,
        const int* __restrict__ offs, const int* __restrict__ ssrc,
        const float* __restrict__ dinv, const float* __restrict__ b1,
        float* __restrict__ hs) {
    int lane = threadIdx.x & 63;
    int node = (blockIdx.x << 2) + (threadIdx.x >> 6);
    const float* xp = xws + lane;
    float acc = xp[node * HD];
    int beg = offs[node], end = offs[node + 1];
    for (int base = beg; base < end; base += 64) {
        int rem = end - base;
        int n = rem < 64 ? rem : 64;
        int idx = (lane < n) ? ssrc[base + lane] : 0;
        int j = 0;
        for (; j + 8 <= n; j += 8) {
            int s0 = __shfl(idx, j+0, 64), s1 = __shfl(idx, j+1, 64);
            int s2 = __shfl(idx, j+2, 64), s3 = __shfl(idx, j+3, 64);
            int s4 = __shfl(idx, j+4, 64), s5 = __shfl(idx, j+5, 64);
            int s6 = __shfl(idx, j+6, 64), s7 = __shfl(idx, j+7, 64);
            float v0 = xp[s0*HD], v1 = xp[s1*HD], v2 = xp[s2*HD], v3 = xp[s3*HD];
            float v4 = xp[s4*HD], v5 = xp[s5*HD], v6 = xp[s6*HD], v7 = xp[s7*HD];
            acc += ((v0+v1)+(v2+v3)) + ((v4+v5)+(v6+v7));
        }
        for (; j < n; ++j) {
            int s = __shfl(idx, j, 64);
            acc += xp[s*HD];
        }
    }
    float dv = dinv[node];
    float h = fmaxf(acc * dv + b1[lane], 0.f);
    hs[node * HD + lane] = h * dv;                 // pre-scale for layer-2 messages
}

// Fallback-path agg2 (used only when ws is too small for the fused path)
__global__ __launch_bounds__(256) void k_agg2(const float* __restrict__ hs,
        const int* __restrict__ offs, const int* __restrict__ ssrc,
        const float* __restrict__ dinv, __hip_bfloat16* __restrict__ gbf) {
    int lane = threadIdx.x & 63;
    int node = (blockIdx.x << 2) + (threadIdx.x >> 6);
    const float* hp = hs + lane;
    float acc = hp[node * HD];
    int beg = offs[node], end = offs[node + 1];
    for (int base = beg; base < end; base += 64) {
        int rem = end - base;
        int n = rem < 64 ? rem : 64;
        int idx = (lane < n) ? ssrc[base + lane] : 0;
        int j = 0;
        for (; j + 8 <= n; j += 8) {
            int s0 = __shfl(idx, j+0, 64), s1 = __shfl(idx, j+1, 64);
            int s2 = __shfl(idx, j+2, 64), s3 = __shfl(idx, j+3, 64);
            int s4 = __shfl(idx, j+4, 64), s5 = __shfl(idx, j+5, 64);
            int s6 = __shfl(idx, j+6, 64), s7 = __shfl(idx, j+7, 64);
            float v0 = hp[s0*HD], v1 = hp[s1*HD], v2 = hp[s2*HD], v3 = hp[s3*HD];
            float v4 = hp[s4*HD], v5 = hp[s5*HD], v6 = hp[s6*HD], v7 = hp[s7*HD];
            acc += ((v0+v1)+(v2+v3)) + ((v4+v5)+(v6+v7));
        }
        for (; j < n; ++j) {
            int s = __shfl(idx, j, 64);
            acc += hp[s*HD];
        }
    }
    gbf[node * HD + lane] = __float2bfloat16(acc * dinv[node]);
}

// ---------------- v1 fused GEMM2 + log_softmax (fallback path, gbf input) ----------------
__global__ __launch_bounds__(512) void k_fused(
        const __hip_bfloat16* __restrict__ gbf,
        const __hip_bfloat16* __restrict__ w2p,
        const float* __restrict__ b2,
        float* __restrict__ out) {
    __shared__ float red[32][8];
    __shared__ float Lsh[32];
    const unsigned short* g  = (const unsigned short*)gbf;
    const unsigned short* wp = (const unsigned short*)w2p;
    int t = threadIdx.x;
    int lane = t & 63, wv = t >> 6;
    int cl = lane & 31, hh = lane >> 5;
    int row0 = blockIdx.x * 32;

    short8 a[4];
#pragma unroll
    for (int kc = 0; kc < 4; ++kc)
        a[kc] = *(const short8*)(g + (row0 + cl) * HD + kc*16 + hh*8);

    float sm[16];
#pragma unroll
    for (int r = 0; r < 16; ++r) sm[r] = 0.f;

    for (int it = 0; it < 32; ++it) {
        int c32 = wv * 32 + it;
        const unsigned short* bp = wp + c32 * 2048 + lane * 8;
        float bias = b2[c32 * 32 + cl];
        f32x16 d;
#pragma unroll
        for (int r = 0; r < 16; ++r) d[r] = 0.f;
#pragma unroll
        for (int kc = 0; kc < 4; ++kc) {
            short8 b = *(const short8*)(bp + kc * 512);
            d = __builtin_amdgcn_mfma_f32_32x32x16_bf16(a[kc], b, d, 0, 0, 0);
        }
#pragma unroll
        for (int r = 0; r < 16; ++r)
            sm[r] += EXP2((d[r] + bias) * LOG2E);
    }
#pragma unroll
    for (int r = 0; r < 16; ++r) {
#pragma unroll
        for (int msk = 1; msk < 32; msk <<= 1)
            sm[r] += __shfl_xor(sm[r], msk, 64);
    }
    if (cl == 0) {
#pragma unroll
        for (int r = 0; r < 16; ++r)
            red[(r & 3) + 8 * (r >> 2) + 4 * hh][wv] = sm[r];
    }
    __syncthreads();
    if (t < 32) {
        float s = 0.f;
#pragma unroll
        for (int j = 0; j < 8; ++j) s += red[t][j];
        Lsh[t] = logf(s);
    }
    __syncthreads();
    float L[16];
#pragma unroll
    for (int r = 0; r < 16; ++r)
        L[r] = Lsh[(r & 3) + 8 * (r >> 2) + 4 * hh];

    for (int it = 0; it < 32; ++it) {
        int c32 = wv * 32 + it;
        const unsigned short* bp = wp + c32 * 2048 + lane * 8;
        float bias = b2[c32 * 32 + cl];
        f32x16 d;
#pragma unroll
        for (int r = 0; r < 16; ++r) d[r] = 0.f;
#pragma unroll
        for (int kc = 0; kc < 4; ++kc) {
            short8 b = *(const short8*)(bp + kc * 512);
            d = __builtin_amdgcn_mfma_f32_32x32x16_bf16(a[kc], b, d, 0, 0, 0);
        }
        float* op = out + (size_t)row0 * NN + c32 * 32 + cl;
#pragma unroll
        for (int r = 0; r < 16; ++r) {
            int rp = (r & 3) + 8 * (r >> 2) + 4 * hh;
            __builtin_nontemporal_store(d[r] + bias - L[r], op + (size_t)rp * NN);
        }
    }
}

// ---------------- v2: agg2 fused into GEMM2 + log_softmax ----------------
__global__ __launch_bounds__(512) void k_fused2(
        const float* __restrict__ hs,
        const int* __restrict__ offs, const int* __restrict__ ssrc,
        const float* __restrict__ dinv,
        const __hip_bfloat16* __restrict__ w2p,
        const float* __restrict__ b2,
        float* __restrict__ out) {
    __shared__ alignas(16) unsigned short gsh[32][72];
    __shared__ float red[32][8];
    __shared__ float Lsh[32];
    const unsigned short* wp = (const unsigned short*)w2p;
    int t = threadIdx.x;
    int lane = t & 63, wv = t >> 6;
    int cl = lane & 31, hh = lane >> 5;
    int row0 = blockIdx.x * 32;

    // ---- fused aggregation head: wave wv aggregates rows wv*4 .. wv*4+3 ----
    const float* hp = hs + lane;
    for (int q = 0; q < 4; ++q) {
        int r = wv * 4 + q;
        int node = row0 + r;
        float acc = hp[node * HD];
        int beg = offs[node], end = offs[node + 1];
        for (int base = beg; base < end; base += 64) {
            int rem = end - base;
            int n = rem < 64 ? rem : 64;
            int idx = (lane < n) ? ssrc[base + lane] : 0;
            int j = 0;
            for (; j + 8 <= n; j += 8) {
                int s0 = __shfl(idx, j+0, 64), s1 = __shfl(idx, j+1, 64);
                int s2 = __shfl(idx, j+2, 64), s3 = __shfl(idx, j+3, 64);
                int s4 = __shfl(idx, j+4, 64), s5 = __shfl(idx, j+5, 64);
                int s6 = __shfl(idx, j+6, 64), s7 = __shfl(idx, j+7, 64);
                float v0 = hp[s0*HD], v1 = hp[s1*HD], v2 = hp[s2*HD], v3 = hp[s3*HD];
                float v4 = hp[s4*HD], v5 = hp[s5*HD], v6 = hp[s6*HD], v7 = hp[s7*HD];
                acc += ((v0+v1)+(v2+v3)) + ((v4+v5)+(v6+v7));
            }
            for (; j < n; ++j) {
                int s = __shfl(idx, j, 64);
                acc += hp[s*HD];
            }
        }
        __hip_bfloat16 hv = __float2bfloat16(acc * dinv[node]);
        gsh[r][lane] = *reinterpret_cast<unsigned short*>(&hv);
    }
    __syncthreads();

    short8 a[4];
#pragma unroll
    for (int kc = 0; kc < 4; ++kc)
        a[kc] = *(const short8*)&gsh[cl][kc * 16 + hh * 8];

    const unsigned short* bpw = wp + (wv * 32) * 2048 + lane * 8;
    const float* bias_c = b2 + wv * 1024 + cl;

    float sm[16];
#pragma unroll
    for (int r = 0; r < 16; ++r) sm[r] = 0.f;

    short8 bc[4];
#pragma unroll
    for (int kc = 0; kc < 4; ++kc) bc[kc] = *(const short8*)(bpw + kc * 512);
    for (int it = 0; it < 32; ++it) {
        int itn = (it + 1) & 31;
        const unsigned short* bq = bpw + itn * 2048;
        short8 bn[4];
#pragma unroll
        for (int kc = 0; kc < 4; ++kc) bn[kc] = *(const short8*)(bq + kc * 512);
        float bias = bias_c[it * 32];
        f32x16 d;
#pragma unroll
        for (int r = 0; r < 16; ++r) d[r] = 0.f;
#pragma unroll
        for (int kc = 0; kc < 4; ++kc)
            d = __builtin_amdgcn_mfma_f32_32x32x16_bf16(a[kc], bc[kc], d, 0, 0, 0);
#pragma unroll
        for (int r = 0; r < 16; ++r)
            sm[r] += EXP2((d[r] + bias) * LOG2E);
#pragma unroll
        for (int kc = 0; kc < 4; ++kc) bc[kc] = bn[kc];
    }
#pragma unroll
    for (int r = 0; r < 16; ++r) {
#pragma unroll
        for (int msk = 1; msk < 32; msk <<= 1)
            sm[r] += __shfl_xor(sm[r], msk, 64);
    }
    if (cl == 0) {
#pragma unroll
        for (int r = 0; r < 16; ++r)
            red[(r & 3) + 8 * (r >> 2) + 4 * hh][wv] = sm[r];
    }
    __syncthreads();
    if (t < 32) {
        float s = 0.f;
#pragma unroll
        for (int j = 0; j < 8; ++j) s += red[t][j];
        Lsh[t] = logf(s);
    }
    __syncthreads();
    float L[16];
#pragma unroll
    for (int r = 0; r < 16; ++r)
        L[r] = Lsh[(r & 3) + 8 * (r >> 2) + 4 * hh];

#pragma unroll
    for (int kc = 0; kc < 4; ++kc) bc[kc] = *(const short8*)(bpw + kc * 512);
    for (int it = 0; it < 32; ++it) {
        int itn = (it + 1) & 31;
        const unsigned short* bq = bpw + itn * 2048;
        short8 bn[4];
#pragma unroll
        for (int kc = 0; kc < 4; ++kc) bn[kc] = *(const short8*)(bq + kc * 512);
        int c32 = wv * 32 + it;
        float bias = bias_c[it * 32];
        f32x16 d;
#pragma unroll
        for (int r = 0; r < 16; ++r) d[r] = 0.f;
#pragma unroll
        for (int kc = 0; kc < 4; ++kc)
            d = __builtin_amdgcn_mfma_f32_32x32x16_bf16(a[kc], bc[kc], d, 0, 0, 0);
        float* op = out + (size_t)row0 * NN + c32 * 32 + cl;
#pragma unroll
        for (int r = 0; r < 16; ++r) {
            int rp = (r & 3) + 8 * (r >> 2) + 4 * hh;
            __builtin_nontemporal_store(d[r] + bias - L[r], op + (size_t)rp * NN);
        }
#pragma unroll
        for (int kc = 0; kc < 4; ++kc) bc[kc] = bn[kc];
    }
}

extern "C" void kernel_launch(void* const* d_in, const int* in_sizes, int n_in,
                              void* d_out, int out_size, void* d_ws, size_t ws_size,
                              hipStream_t stream) {
    const float* x  = (const float*)d_in[0];
    const int*   ei = (const int*)d_in[1];
    const float* W1 = (const float*)d_in[2];
    const float* b1 = (const float*)d_in[3];
    const float* W2 = (const float*)d_in[4];
    const float* b2 = (const float*)d_in[5];
    float* out = (float*)d_out;
    int E = in_sizes[1] / 2;
    const int* esrc = ei;
    const int* edst = ei + E;

    char* w = (char*)d_ws;
    int*   cnt    = (int*)(w);
    int*   offs   = (int*)(w + (32 << 10));
    int*   cursor = (int*)(w + (68 << 10));
    float* dinv   = (float*)(w + (100 << 10));
    __hip_bfloat16* w2p = (__hip_bfloat16*)(w + (192 << 10));

    size_t total = (size_t)NN * NN;
    size_t need_fused = (size_t)(192 << 10) + (1 << 20) + (size_t)NN * HD * sizeof(float);
    bool fused_path = ws_size >= need_fused;

    int cb = ((E + 3) / 4 + 255) / 256;          // count/scatter blocks (int4 edges)
    int pb = (HD * NN / 8) / 256;                // pack blocks (256)
    int gb = NN / 16;                            // gemm1 blocks

    k_zero   <<<1, 1024, 0, stream>>>(cnt);
    k_front  <<<pb + cb, 256, 0, stream>>>(W2, w2p, edst, E, cnt, pb);
    k_scan   <<<1, 1024, 0, stream>>>(cnt, offs, cursor, dinv);

    if (fused_path) {
        // hs lives in ws (k_fused2 reads it while writing all of out);
        // xws/ssrc are dead before k_fused2 -> out tail is safe for them.
        float* hs   = (float*)(w + (192 << 10) + (1 << 20));
        float* xws  = out + total - (size_t)NN * HD;
        int*   ssrc = (int*)xws - E;
        k_mid    <<<gb + cb, 256, 0, stream>>>(x, W1, dinv, xws, esrc, edst, E, cursor, ssrc);
        k_agg1   <<<NN / 4, 256, 0, stream>>>(xws, offs, ssrc, dinv, b1, hs);
        k_fused2 <<<NN / 32, 512, 0, stream>>>(hs, offs, ssrc, dinv, w2p, b2, out);
    } else {
        // v1-style fallback (agg2 + k_fused), intermediates in out tail.
        __hip_bfloat16* gbf = (__hip_bfloat16*)(w + (192 << 10) + (1 << 20));
        float* hs   = out + total - (size_t)NN * HD;
        float* xws  = hs  - (size_t)NN * HD;
        int*   ssrc = (int*)xws - E;
        k_mid    <<<gb + cb, 256, 0, stream>>>(x, W1, dinv, xws, esrc, edst, E, cursor, ssrc);
        k_agg1   <<<NN / 4, 256, 0, stream>>>(xws, offs, ssrc, dinv, b1, hs);
        k_agg2   <<<NN / 4, 256, 0, stream>>>(hs, offs, ssrc, dinv, gbf);
        k_fused  <<<NN / 32, 512, 0, stream>>>(gbf, w2p, b2, out);
    }
}